// Round 1
// baseline (1268.851 us; speedup 1.0000x reference)
//
#include <hip/hip_runtime.h>

// BandVQ forward: B=8, NB=3, D=512, T=2048, K=1024
// x:        [B, NB, D, T] f32
// codebook: [NB, K, D]    f32
// out: quantized [B,NB,D,T] f32 | codes [B,NB,T] (written as float) | commit_loss (1 float)

#define B_ 8
#define NB_ 3
#define D_ 512
#define T_ 2048
#define K_ 1024
#define ROWS_ (B_*NB_*T_)          // 49152
#define Q_ELEMS_ ((size_t)B_*NB_*D_*T_)  // 25165824
#define MARGIN_ 0.1f

// ---------------------------------------------------------------- e2 kernel
__global__ __launch_bounds__(256) void e2_kernel(const float* __restrict__ cb,
                                                 float* __restrict__ e2) {
    int row = blockIdx.x * 4 + (threadIdx.x >> 6);   // NB_*K_ = 3072 rows
    int lane = threadIdx.x & 63;
    if (row >= NB_ * K_) return;
    const float* p = cb + (size_t)row * D_;
    double s = 0.0;
    for (int d = lane; d < D_; d += 64) {
        float v = p[d];
        s += (double)v * (double)v;
    }
    for (int off = 32; off > 0; off >>= 1) s += __shfl_down(s, off, 64);
    if (lane == 0) e2[row] = (float)s;
}

// ------------------------------------------------------------ argmin kernel
// Per block: one (b,n) pair, 64 consecutive t. Loops over all K in 64-wide
// tiles, computing s = e2[k] - 2*dot(x_t, e_k) and tracking (min1, idx, min2).
__global__ __launch_bounds__(256) void argmin_kernel(
    const float* __restrict__ x, const float* __restrict__ cb,
    const float* __restrict__ e2,
    float* __restrict__ wm1, float* __restrict__ wm2, int* __restrict__ wi1) {

    int bn = blockIdx.y;             // b*NB + n
    int n  = bn % NB_;
    int t0 = blockIdx.x * 64;
    const float* xb  = x  + (size_t)bn * D_ * T_;
    const float* cbb = cb + (size_t)n * K_ * D_;
    const float* e2b = e2 + n * K_;

    __shared__ float xs[32][64];     // [dd][t]
    __shared__ float es[32][68];     // [dd][k], stride 68 keeps 16B-aligned rows
    __shared__ float rm1[64][16];
    __shared__ float rm2[64][16];
    __shared__ int   ri1[64][16];

    int tid = threadIdx.x;
    int tx = tid & 15, ty = tid >> 4;

    float m1[4], m2[4];
    int   i1[4];
#pragma unroll
    for (int r = 0; r < 4; ++r) { m1[r] = 3.4e38f; m2[r] = 3.4e38f; i1[r] = 0; }

    for (int kt = 0; kt < K_ / 64; ++kt) {
        int k0 = kt * 64;
        float acc[4][4];
#pragma unroll
        for (int r = 0; r < 4; ++r)
#pragma unroll
            for (int c = 0; c < 4; ++c) acc[r][c] = 0.f;

        for (int d0 = 0; d0 < D_; d0 += 32) {
            __syncthreads();
#pragma unroll
            for (int i = 0; i < 8; ++i) {          // xs: 2048 elems
                int idx = tid + 256 * i;
                int dd = idx >> 6, lt = idx & 63;
                xs[dd][lt] = xb[(size_t)(d0 + dd) * T_ + t0 + lt];
            }
#pragma unroll
            for (int i = 0; i < 8; ++i) {          // es: 2048 elems
                int idx = tid + 256 * i;
                int kk = idx >> 5, dd = idx & 31;
                es[dd][kk] = cbb[(size_t)(k0 + kk) * D_ + d0 + dd];
            }
            __syncthreads();
#pragma unroll
            for (int dd = 0; dd < 32; ++dd) {
                float4 a = *reinterpret_cast<const float4*>(&xs[dd][ty * 4]);
                float4 b = *reinterpret_cast<const float4*>(&es[dd][tx * 4]);
                acc[0][0] += a.x * b.x; acc[0][1] += a.x * b.y;
                acc[0][2] += a.x * b.z; acc[0][3] += a.x * b.w;
                acc[1][0] += a.y * b.x; acc[1][1] += a.y * b.y;
                acc[1][2] += a.y * b.z; acc[1][3] += a.y * b.w;
                acc[2][0] += a.z * b.x; acc[2][1] += a.z * b.y;
                acc[2][2] += a.z * b.z; acc[2][3] += a.z * b.w;
                acc[3][0] += a.w * b.x; acc[3][1] += a.w * b.y;
                acc[3][2] += a.w * b.z; acc[3][3] += a.w * b.w;
            }
        }
        // fold this k-tile into running two-min (k ascending per thread)
#pragma unroll
        for (int c = 0; c < 4; ++c) {
            int k = k0 + tx * 4 + c;
            float ev = e2b[k];
#pragma unroll
            for (int r = 0; r < 4; ++r) {
                float v = ev - 2.0f * acc[r][c];
                if (v < m1[r]) { m2[r] = m1[r]; m1[r] = v; i1[r] = k; }
                else if (v < m2[r]) m2[r] = v;
            }
        }
    }

    // cross-thread (tx) reduction per t-row
#pragma unroll
    for (int r = 0; r < 4; ++r) {
        rm1[ty * 4 + r][tx] = m1[r];
        rm2[ty * 4 + r][tx] = m2[r];
        ri1[ty * 4 + r][tx] = i1[r];
    }
    __syncthreads();
    if (tid < 64) {
        float fm1 = rm1[tid][0], fm2 = rm2[tid][0];
        int   fi  = ri1[tid][0];
        for (int j = 1; j < 16; ++j) {
            float bm1 = rm1[tid][j], bm2 = rm2[tid][j];
            int   bi  = ri1[tid][j];
            if (bm1 < fm1 || (bm1 == fm1 && bi < fi)) {
                fm2 = fminf(fm1, bm2); fm1 = bm1; fi = bi;
            } else {
                fm2 = fminf(fm2, bm1);
            }
        }
        int row = bn * T_ + t0 + tid;
        wm1[row] = fm1; wm2[row] = fm2; wi1[row] = fi;
    }
}

// ------------------------------------------------------------- zero loss
__global__ void zero_loss(float* loss) { *loss = 0.f; }

// ------------------------------------------------- gather + refine + loss
__global__ __launch_bounds__(256) void gather_kernel(
    const float* __restrict__ x, const float* __restrict__ cb,
    const float* __restrict__ wm1, const float* __restrict__ wm2,
    const int* __restrict__ wi1,
    float* __restrict__ outq, float* __restrict__ outc,
    float* __restrict__ loss) {

    int bn = blockIdx.y;
    int n  = bn % NB_;
    int t0 = blockIdx.x * 64;
    int tid = threadIdx.x;
    const float* xb  = x  + (size_t)bn * D_ * T_;
    const float* cbb = cb + (size_t)n * K_ * D_;

    __shared__ int codes_sh[64];
    __shared__ int slow_any;
    __shared__ double rv[256];
    __shared__ int    ri[256];
    __shared__ float  qsh[64][65];
    __shared__ float  wsum[4];

    if (tid == 0) slow_any = 0;
    __syncthreads();
    if (tid < 64) {
        int row = bn * T_ + t0 + tid;
        float g = wm2[row] - wm1[row];
        int c = wi1[row];
        if (g < MARGIN_) { codes_sh[tid] = -1; slow_any = 1; }
        else codes_sh[tid] = c;
    }
    __syncthreads();

    if (slow_any) {
        for (int r = 0; r < 64; ++r) {
            if (codes_sh[r] >= 0) continue;   // uniform branch (shared)
            // fp64 exact rescan of all K for this row
            double best = 1e300; int bi = K_;
            for (int k = tid; k < K_; k += 256) {
                const float* cr = cbb + (size_t)k * D_;
                double s = 0.0;
                for (int d = 0; d < D_; ++d) {
                    double diff = (double)xb[(size_t)d * T_ + t0 + r] - (double)cr[d];
                    s += diff * diff;
                }
                if (s < best) { best = s; bi = k; }   // k ascending per thread
            }
            rv[tid] = best; ri[tid] = bi;
            __syncthreads();
            for (int s2 = 128; s2 > 0; s2 >>= 1) {
                if (tid < s2) {
                    if (rv[tid + s2] < rv[tid] ||
                        (rv[tid + s2] == rv[tid] && ri[tid + s2] < ri[tid])) {
                        rv[tid] = rv[tid + s2]; ri[tid] = ri[tid + s2];
                    }
                }
                __syncthreads();
            }
            if (tid == 0) codes_sh[r] = ri[0];
            __syncthreads();
        }
    }

    if (tid < 64) outc[bn * T_ + t0 + tid] = (float)codes_sh[tid];

    float lsum = 0.f;
    int r4 = tid >> 6, dd0 = tid & 63;
    int lt = tid & 63, l4 = tid >> 6;
    for (int d0 = 0; d0 < D_; d0 += 64) {
        __syncthreads();
        for (int r = r4; r < 64; r += 4)
            qsh[r][dd0] = cbb[(size_t)codes_sh[r] * D_ + d0 + dd0];
        __syncthreads();
#pragma unroll
        for (int j = 0; j < 16; ++j) {
            int dd = l4 + 4 * j;
            float q = qsh[lt][dd];
            size_t xi = ((size_t)bn * D_ + d0 + dd) * T_ + t0 + lt;
            float xv = x[xi];
            outq[xi] = q;
            float df = q - xv;
            lsum += df * df;
        }
    }

    for (int off = 32; off > 0; off >>= 1) lsum += __shfl_down(lsum, off, 64);
    if ((tid & 63) == 0) wsum[tid >> 6] = lsum;
    __syncthreads();
    if (tid == 0) {
        float tot = wsum[0] + wsum[1] + wsum[2] + wsum[3];
        atomicAdd(loss, tot * (1.0f / (float)Q_ELEMS_));
    }
}

// ---------------------------------------------------------------- launcher
extern "C" void kernel_launch(void* const* d_in, const int* in_sizes, int n_in,
                              void* d_out, int out_size, void* d_ws, size_t ws_size,
                              hipStream_t stream) {
    (void)in_sizes; (void)n_in; (void)out_size; (void)ws_size;
    const float* x  = (const float*)d_in[0];
    const float* cb = (const float*)d_in[1];
    float* out = (float*)d_out;

    float* outq = out;                       // [B,NB,D,T]
    float* outc = out + Q_ELEMS_;            // [B,NB,T] as float
    float* lossp = out + Q_ELEMS_ + ROWS_;   // scalar

    float* ws  = (float*)d_ws;
    float* e2  = ws;                         // NB_*K_
    float* wm1 = e2 + NB_ * K_;              // ROWS_
    float* wm2 = wm1 + ROWS_;                // ROWS_
    int*   wi1 = (int*)(wm2 + ROWS_);        // ROWS_

    e2_kernel<<<dim3(768), dim3(256), 0, stream>>>(cb, e2);
    argmin_kernel<<<dim3(T_ / 64, B_ * NB_), dim3(256), 0, stream>>>(
        x, cb, e2, wm1, wm2, wi1);
    zero_loss<<<dim3(1), dim3(1), 0, stream>>>(lossp);
    gather_kernel<<<dim3(T_ / 64, B_ * NB_), dim3(256), 0, stream>>>(
        x, cb, wm1, wm2, wi1, outq, outc, lossp);
}

// Round 2
// 490.774 us; speedup vs baseline: 2.5854x; 2.5854x over previous
//
#include <hip/hip_runtime.h>

// BandVQ forward: B=8, NB=3, D=512, T=2048, K=1024
// x:        [B, NB, D, T] f32
// codebook: [NB, K, D]    f32
// out: quantized [B,NB,D,T] f32 | codes [B,NB,T] (as float) | commit_loss (1 float)

#define B_ 8
#define NB_ 3
#define D_ 512
#define T_ 2048
#define K_ 1024
#define BN_ (B_*NB_)               // 24
#define ROWS_ (BN_*T_)             // 49152
#define Q_ELEMS_ ((size_t)BN_*D_*T_)  // 25165824
#define MARGIN_ 0.02f

typedef __attribute__((ext_vector_type(4))) float f32x4;
typedef __attribute__((ext_vector_type(8))) short bf16x8;
typedef __attribute__((ext_vector_type(4))) unsigned int u32x4;

__device__ inline unsigned short f2bf(float f) {
    unsigned u = __builtin_bit_cast(unsigned, f);
    unsigned r = (u + 0x7FFFu + ((u >> 16) & 1u)) >> 16;
    return (unsigned short)r;
}
__device__ inline float bf2f(unsigned short h) {
    unsigned u = ((unsigned)h) << 16;
    return __builtin_bit_cast(float, u);
}
__device__ inline void gld16(const void* g, void* l) {
    __builtin_amdgcn_global_load_lds(
        (const __attribute__((address_space(1))) unsigned int*)g,
        (__attribute__((address_space(3))) unsigned int*)l, 16, 0, 0);
}

// -------------------------------------------------- convert codebook + e2
// cb [NB][K][D] f32 -> Eh,El [NB][K][D] bf16 (16B-chunk swizzled within each
// 128B d-slice: logical chunk c stored at c^(k&7)), e2 [NB*K] f32 (fp64 acc).
__global__ __launch_bounds__(256) void convert_e(
    const float* __restrict__ cb,
    unsigned short* __restrict__ Eh, unsigned short* __restrict__ El,
    float* __restrict__ e2) {
    int row = blockIdx.x * 4 + (threadIdx.x >> 6);   // 0..3071 = n*K + k
    int lane = threadIdx.x & 63;
    if (row >= NB_ * K_) return;
    int s = lane >> 3, c = lane & 7;
    const float* p = cb + (size_t)row * D_ + s * 64 + c * 8;
    float v[8];
#pragma unroll
    for (int e = 0; e < 8; ++e) v[e] = p[e];
    double sum = 0.0;
#pragma unroll
    for (int e = 0; e < 8; ++e) sum += (double)v[e] * (double)v[e];
    unsigned int uh[4], ul[4];
#pragma unroll
    for (int q = 0; q < 4; ++q) {
        unsigned short h0 = f2bf(v[2*q]), h1 = f2bf(v[2*q+1]);
        float l0 = v[2*q] - bf2f(h0), l1 = v[2*q+1] - bf2f(h1);
        uh[q] = (unsigned)h0 | ((unsigned)h1 << 16);
        ul[q] = (unsigned)f2bf(l0) | ((unsigned)f2bf(l1) << 16);
    }
    size_t pos = (size_t)row * 1024 + s * 128 + ((c ^ (row & 7)) * 16);
    *(u32x4*)((char*)Eh + pos) = u32x4{uh[0], uh[1], uh[2], uh[3]};
    *(u32x4*)((char*)El + pos) = u32x4{ul[0], ul[1], ul[2], ul[3]};
    for (int off = 32; off > 0; off >>= 1) sum += __shfl_down(sum, off, 64);
    if (lane == 0) e2[row] = (float)sum;
}

// -------------------------------------------------- convert + transpose x
// x [bn][D][T] f32 -> Xh,Xl [bn][T][D] bf16, same chunk swizzle keyed by t&7.
__global__ __launch_bounds__(256) void convert_x(
    const float* __restrict__ x,
    unsigned short* __restrict__ Xh, unsigned short* __restrict__ Xl) {
    int t0 = blockIdx.x * 64;       // 32 tiles
    int d0 = blockIdx.y * 64;       // 8 tiles (slice s = blockIdx.y)
    int bn = blockIdx.z;            // 24
    int tid = threadIdx.x;
    __shared__ float tile[64][65];
#pragma unroll
    for (int i = 0; i < 16; ++i) {
        int idx = tid + 256 * i;
        int dd = idx >> 6, tt = idx & 63;
        tile[dd][tt] = x[((size_t)bn * D_ + d0 + dd) * T_ + t0 + tt];
    }
    __syncthreads();
    int tt = tid >> 2, cp = tid & 3;
    size_t rowbyte = ((size_t)bn * T_ + t0 + tt) * 1024 + (size_t)blockIdx.y * 128;
    int sw = (t0 + tt) & 7;   // == tt&7 (t0 mult of 64)
#pragma unroll
    for (int cc = 0; cc < 2; ++cc) {
        int c = cp * 2 + cc;
        unsigned int uh[4], ul[4];
#pragma unroll
        for (int q = 0; q < 4; ++q) {
            float v0 = tile[c * 8 + 2*q][tt], v1 = tile[c * 8 + 2*q + 1][tt];
            unsigned short h0 = f2bf(v0), h1 = f2bf(v1);
            float l0 = v0 - bf2f(h0), l1 = v1 - bf2f(h1);
            uh[q] = (unsigned)h0 | ((unsigned)h1 << 16);
            ul[q] = (unsigned)f2bf(l0) | ((unsigned)f2bf(l1) << 16);
        }
        size_t pos = rowbyte + ((c ^ sw) * 16);
        *(u32x4*)((char*)Xh + pos) = u32x4{uh[0], uh[1], uh[2], uh[3]};
        *(u32x4*)((char*)Xl + pos) = u32x4{ul[0], ul[1], ul[2], ul[3]};
    }
}

// ------------------------------------------------------------- MFMA GEMM
// Per block: one (bn, t-tile of 128, k-half of 512). Loops 4 k-chunks of 128;
// for each: BK=64 d-steps staged via global_load_lds (wave w stages buffer w),
// 3-pass split-bf16 MFMA, two-min fold in epilogue.
__global__ __launch_bounds__(256, 2) void vq_gemm(
    const unsigned short* __restrict__ Xh, const unsigned short* __restrict__ Xl,
    const unsigned short* __restrict__ Eh, const unsigned short* __restrict__ El,
    const float* __restrict__ e2,
    float* __restrict__ pm1, float* __restrict__ pm2, int* __restrict__ pi1) {

    __shared__ u32x4 ldsq[65536 / 16];   // A_hi | A_lo | B_hi | B_lo, 16KB each
    __shared__ float mm1[2][128], mm2[2][128];
    __shared__ int   mi_[2][128];
    char* ldsbuf = (char*)ldsq;

    int bx = blockIdx.x;        // t-tile 0..15
    int by = blockIdx.y;        // k-half 0..1
    int bn = blockIdx.z;        // 0..23
    int band = bn % NB_;
    int tid = threadIdx.x;
    int lane = tid & 63, wid = tid >> 6;
    int wm = wid >> 1, wn = wid & 1;
    int rl = lane & 15, cl = lane >> 4;
    int sw = rl & 7;

    // per-lane staging source base (wave w stages buffer w)
    const char* srcbase;
    size_t rowbase;
    if (wid < 2) {
        srcbase = (const char*)(wid == 0 ? Xh : Xl);
        rowbase = (size_t)bn * T_ + (size_t)bx * 128;
    } else {
        srcbase = (const char*)(wid == 2 ? Eh : El);
        rowbase = (size_t)band * K_ + (size_t)by * 512;
    }
    const char* lane_src0 = srcbase + (rowbase + (lane >> 3)) * 1024 + (lane & 7) * 16;
    char* ldsw = ldsbuf + wid * 16384;

    const char* Ab_hi = ldsbuf;
    const char* Ab_lo = ldsbuf + 16384;
    const char* Bb_hi = ldsbuf + 32768;
    const char* Bb_lo = ldsbuf + 49152;

    float tm1[16], tm2[16];
    int ti1[16];
#pragma unroll
    for (int i = 0; i < 16; ++i) { tm1[i] = 3.4e38f; tm2[i] = 3.4e38f; ti1[i] = 0x7fffffff; }

    const float* e2b = e2 + band * K_;

    for (int kc = 0; kc < 4; ++kc) {
        const char* lsrc = lane_src0 + ((wid >= 2) ? ((size_t)kc << 17) : 0);
        f32x4 acc[4][4];
#pragma unroll
        for (int m = 0; m < 4; ++m)
#pragma unroll
            for (int n = 0; n < 4; ++n) acc[m][n] = f32x4{0.f, 0.f, 0.f, 0.f};

        for (int s = 0; s < 8; ++s) {
            __syncthreads();
            const char* ss = lsrc + s * 128;
#pragma unroll
            for (int q = 0; q < 16; ++q)
                gld16(ss + (size_t)q * 8192, ldsw + q * 1024);
            __syncthreads();

            int arow = (wm * 64 + rl) * 128;
            int brow = (wn * 64 + rl) * 128;
#pragma unroll
            for (int kk = 0; kk < 2; ++kk) {
                int chunk = ((kk * 4 + cl) ^ sw) * 16;
                int aoff = arow + chunk;
                int boff = brow + chunk;
                bf16x8 bh[4], bl2[4];
#pragma unroll
                for (int n = 0; n < 4; ++n) {
                    bh[n]  = *(const bf16x8*)(Bb_hi + boff + n * 2048);
                    bl2[n] = *(const bf16x8*)(Bb_lo + boff + n * 2048);
                }
#pragma unroll
                for (int m = 0; m < 4; ++m) {
                    bf16x8 ah = *(const bf16x8*)(Ab_hi + aoff + m * 2048);
                    bf16x8 al = *(const bf16x8*)(Ab_lo + aoff + m * 2048);
#pragma unroll
                    for (int n = 0; n < 4; ++n) {
                        acc[m][n] = __builtin_amdgcn_mfma_f32_16x16x32_bf16(ah, bh[n],  acc[m][n], 0, 0, 0);
                        acc[m][n] = __builtin_amdgcn_mfma_f32_16x16x32_bf16(ah, bl2[n], acc[m][n], 0, 0, 0);
                        acc[m][n] = __builtin_amdgcn_mfma_f32_16x16x32_bf16(al, bh[n],  acc[m][n], 0, 0, 0);
                    }
                }
            }
        }

        // fold chunk into running two-min (k ascending: nf asc, kc asc)
        int kbase = by * 512 + kc * 128 + wn * 64 + rl;
        float ev[4];
#pragma unroll
        for (int nf = 0; nf < 4; ++nf) ev[nf] = e2b[kbase + nf * 16];
#pragma unroll
        for (int m = 0; m < 4; ++m)
#pragma unroll
            for (int r = 0; r < 4; ++r) {
                int id = m * 4 + r;
#pragma unroll
                for (int nf = 0; nf < 4; ++nf) {
                    float v = ev[nf] - 2.0f * acc[m][nf][r];
                    int k = kbase + nf * 16;
                    if (v < tm1[id]) { tm2[id] = tm1[id]; tm1[id] = v; ti1[id] = k; }
                    else if (v < tm2[id]) tm2[id] = v;
                }
            }
    }

    // butterfly merge across the 16 (lane&15) columns
#pragma unroll
    for (int id = 0; id < 16; ++id) {
#pragma unroll
        for (int st = 1; st < 16; st <<= 1) {
            float om1 = __shfl_xor(tm1[id], st, 64);
            float om2 = __shfl_xor(tm2[id], st, 64);
            int   oi  = __shfl_xor(ti1[id], st, 64);
            if (om1 < tm1[id] || (om1 == tm1[id] && oi < ti1[id])) {
                tm2[id] = fminf(tm1[id], om2); tm1[id] = om1; ti1[id] = oi;
            } else {
                tm2[id] = fminf(tm2[id], om1);
            }
        }
    }
    if (rl == 0) {
#pragma unroll
        for (int m = 0; m < 4; ++m)
#pragma unroll
            for (int r = 0; r < 4; ++r) {
                int row = wm * 64 + m * 16 + cl * 4 + r;
                mm1[wn][row] = tm1[m * 4 + r];
                mm2[wn][row] = tm2[m * 4 + r];
                mi_[wn][row] = ti1[m * 4 + r];
            }
    }
    __syncthreads();
    if (tid < 128) {
        float a1 = mm1[0][tid], a2 = mm2[0][tid]; int ai = mi_[0][tid];
        float b1 = mm1[1][tid], b2 = mm2[1][tid]; int bi = mi_[1][tid];
        float m1, m2; int i1;
        if (b1 < a1) { m1 = b1; i1 = bi; m2 = fminf(a1, b2); }
        else         { m1 = a1; i1 = ai; m2 = fminf(a2, b1); }
        size_t rowg = (size_t)bn * T_ + (size_t)bx * 128 + tid;
        pm1[rowg * 2 + by] = m1; pm2[rowg * 2 + by] = m2; pi1[rowg * 2 + by] = i1;
    }
}

// ------------------------------------------------------------- zero loss
__global__ void zero_loss(float* loss) { *loss = 0.f; }

// ------------------------------------------- gather + refine + loss
__global__ __launch_bounds__(256) void gather_kernel(
    const float* __restrict__ x, const float* __restrict__ cb,
    const float* __restrict__ pm1, const float* __restrict__ pm2,
    const int* __restrict__ pi1,
    float* __restrict__ outq, float* __restrict__ outc,
    float* __restrict__ loss) {

    int bn = blockIdx.y;
    int n  = bn % NB_;
    int t0 = blockIdx.x * 64;
    int tid = threadIdx.x;
    const float* xb  = x  + (size_t)bn * D_ * T_;
    const float* cbb = cb + (size_t)n * K_ * D_;

    __shared__ int codes_sh[64];
    __shared__ int slow_any;
    __shared__ double rv[256];
    __shared__ int    ri[256];
    __shared__ float  qsh[64][65];
    __shared__ float  wsum[4];

    if (tid == 0) slow_any = 0;
    __syncthreads();
    if (tid < 64) {
        size_t rowg = (size_t)bn * T_ + t0 + tid;
        float a1 = pm1[rowg * 2], a2 = pm2[rowg * 2]; int ai = pi1[rowg * 2];
        float b1 = pm1[rowg * 2 + 1], b2 = pm2[rowg * 2 + 1]; int bi = pi1[rowg * 2 + 1];
        float m1, m2; int i1;
        if (b1 < a1) { m1 = b1; i1 = bi; m2 = fminf(a1, b2); }
        else         { m1 = a1; i1 = ai; m2 = fminf(a2, b1); }
        if (m2 - m1 < MARGIN_) { codes_sh[tid] = -1; slow_any = 1; }
        else codes_sh[tid] = i1;
    }
    __syncthreads();

    if (slow_any) {
        for (int r = 0; r < 64; ++r) {
            if (codes_sh[r] >= 0) continue;   // uniform (shared)
            double best = 1e300; int bi = K_;
            for (int k = tid; k < K_; k += 256) {
                const float* cr = cbb + (size_t)k * D_;
                double s = 0.0;
                for (int d = 0; d < D_; ++d) {
                    double diff = (double)xb[(size_t)d * T_ + t0 + r] - (double)cr[d];
                    s += diff * diff;
                }
                if (s < best) { best = s; bi = k; }
            }
            rv[tid] = best; ri[tid] = bi;
            __syncthreads();
            for (int s2 = 128; s2 > 0; s2 >>= 1) {
                if (tid < s2) {
                    if (rv[tid + s2] < rv[tid] ||
                        (rv[tid + s2] == rv[tid] && ri[tid + s2] < ri[tid])) {
                        rv[tid] = rv[tid + s2]; ri[tid] = ri[tid + s2];
                    }
                }
                __syncthreads();
            }
            if (tid == 0) codes_sh[r] = ri[0];
            __syncthreads();
        }
    }

    if (tid < 64) outc[(size_t)bn * T_ + t0 + tid] = (float)codes_sh[tid];

    float lsum = 0.f;
    int r4 = tid >> 6, dd0 = tid & 63;
    int lt = tid & 63, l4 = tid >> 6;
    for (int d0 = 0; d0 < D_; d0 += 64) {
        __syncthreads();
        for (int r = r4; r < 64; r += 4)
            qsh[r][dd0] = cbb[(size_t)codes_sh[r] * D_ + d0 + dd0];
        __syncthreads();
#pragma unroll
        for (int j = 0; j < 16; ++j) {
            int dd = l4 + 4 * j;
            float q = qsh[lt][dd];
            size_t xi = ((size_t)bn * D_ + d0 + dd) * T_ + t0 + lt;
            float xv = x[xi];
            outq[xi] = q;
            float df = q - xv;
            lsum += df * df;
        }
    }

    for (int off = 32; off > 0; off >>= 1) lsum += __shfl_down(lsum, off, 64);
    if ((tid & 63) == 0) wsum[tid >> 6] = lsum;
    __syncthreads();
    if (tid == 0) {
        float tot = wsum[0] + wsum[1] + wsum[2] + wsum[3];
        atomicAdd(loss, tot * (1.0f / (float)Q_ELEMS_));
    }
}

// ---------------------------------------------------------------- launcher
extern "C" void kernel_launch(void* const* d_in, const int* in_sizes, int n_in,
                              void* d_out, int out_size, void* d_ws, size_t ws_size,
                              hipStream_t stream) {
    (void)in_sizes; (void)n_in; (void)out_size; (void)ws_size;
    const float* x  = (const float*)d_in[0];
    const float* cb = (const float*)d_in[1];
    float* out = (float*)d_out;

    float* outq  = out;                       // [B,NB,D,T]
    float* outc  = out + Q_ELEMS_;            // [B,NB,T] as float
    float* lossp = out + Q_ELEMS_ + ROWS_;    // scalar

    // split-bf16 x lives in the (not-yet-written) quantized output region:
    // Xh = first half (bf16), Xl = second half. Exactly Q_ELEMS_ floats total.
    unsigned short* Xh = (unsigned short*)d_out;
    unsigned short* Xl = Xh + Q_ELEMS_;

    char* ws = (char*)d_ws;
    unsigned short* Eh = (unsigned short*)ws;                    // 3 MiB
    unsigned short* El = Eh + (size_t)NB_ * K_ * D_;             // 3 MiB
    float* e2  = (float*)(El + (size_t)NB_ * K_ * D_);           // 12 KiB
    float* pm1 = e2 + NB_ * K_;                                  // 384 KiB
    float* pm2 = pm1 + (size_t)ROWS_ * 2;
    int*   pi1 = (int*)(pm2 + (size_t)ROWS_ * 2);

    convert_e<<<dim3(768), dim3(256), 0, stream>>>(cb, Eh, El, e2);
    convert_x<<<dim3(32, 8, 24), dim3(256), 0, stream>>>(x, Xh, Xl);
    vq_gemm<<<dim3(16, 2, 24), dim3(256), 0, stream>>>(Xh, Xl, Eh, El, e2, pm1, pm2, pi1);
    zero_loss<<<dim3(1), dim3(1), 0, stream>>>(lossp);
    gather_kernel<<<dim3(32, 24), dim3(256), 0, stream>>>(
        x, cb, pm1, pm2, pi1, outq, outc, lossp);
}

// Round 3
// 431.761 us; speedup vs baseline: 2.9388x; 1.1367x over previous
//
#include <hip/hip_runtime.h>

// BandVQ forward: B=8, NB=3, D=512, T=2048, K=1024
// x:        [B, NB, D, T] f32
// codebook: [NB, K, D]    f32
// out: quantized [B,NB,D,T] f32 | codes [B,NB,T] (as float) | commit_loss (1 float)

#define B_ 8
#define NB_ 3
#define D_ 512
#define T_ 2048
#define K_ 1024
#define BN_ (B_*NB_)               // 24
#define ROWS_ (BN_*T_)             // 49152
#define Q_ELEMS_ ((size_t)BN_*D_*T_)  // 25165824
#define MARGIN_ 0.02f

typedef __attribute__((ext_vector_type(4))) float f32x4;
typedef __attribute__((ext_vector_type(8))) short bf16x8;
typedef __attribute__((ext_vector_type(4))) unsigned int u32x4;

__device__ inline unsigned short f2bf(float f) {
    unsigned u = __builtin_bit_cast(unsigned, f);
    unsigned r = (u + 0x7FFFu + ((u >> 16) & 1u)) >> 16;
    return (unsigned short)r;
}
__device__ inline float bf2f(unsigned short h) {
    unsigned u = ((unsigned)h) << 16;
    return __builtin_bit_cast(float, u);
}
__device__ inline void gld16(const void* g, void* l) {
    __builtin_amdgcn_global_load_lds(
        (const __attribute__((address_space(1))) unsigned int*)g,
        (__attribute__((address_space(3))) unsigned int*)l, 16, 0, 0);
}

// ----------------------------------------------------------- zero ws/loss
__global__ void zero_ws(float* __restrict__ x2g, float* __restrict__ lossp) {
    int i = blockIdx.x * 256 + threadIdx.x;
    if (i < ROWS_) x2g[i] = 0.f;
    if (i == 0) *lossp = 0.f;
}

// -------------------------------------------------- convert codebook + e2
// cb [NB][K][D] f32 -> Eh,El [NB][K][D] bf16 plain row-major, e2 fp64-acc.
__global__ __launch_bounds__(256) void convert_e(
    const float* __restrict__ cb,
    unsigned short* __restrict__ Eh, unsigned short* __restrict__ El,
    float* __restrict__ e2) {
    int row = blockIdx.x * 4 + (threadIdx.x >> 6);   // 0..3071 = n*K + k
    int lane = threadIdx.x & 63;
    const float* p = cb + (size_t)row * D_ + lane * 8;
    float v[8];
#pragma unroll
    for (int e = 0; e < 8; ++e) v[e] = p[e];
    double sum = 0.0;
#pragma unroll
    for (int e = 0; e < 8; ++e) sum += (double)v[e] * (double)v[e];
    unsigned int uh[4], ul[4];
#pragma unroll
    for (int q = 0; q < 4; ++q) {
        unsigned short h0 = f2bf(v[2*q]), h1 = f2bf(v[2*q+1]);
        float l0 = v[2*q] - bf2f(h0), l1 = v[2*q+1] - bf2f(h1);
        uh[q] = (unsigned)h0 | ((unsigned)h1 << 16);
        ul[q] = (unsigned)f2bf(l0) | ((unsigned)f2bf(l1) << 16);
    }
    size_t pos = (size_t)row * 1024 + lane * 16;
    *(u32x4*)((char*)Eh + pos) = u32x4{uh[0], uh[1], uh[2], uh[3]};
    *(u32x4*)((char*)El + pos) = u32x4{ul[0], ul[1], ul[2], ul[3]};
    for (int off = 32; off > 0; off >>= 1) sum += __shfl_down(sum, off, 64);
    if (lane == 0) e2[row] = (float)sum;
}

// -------------------------------------------------- convert + transpose x
// x [bn][D][T] f32 -> Xh,Xl [bn][T][D] bf16 plain; accumulate per-row x^2.
__global__ __launch_bounds__(256) void convert_x(
    const float* __restrict__ x,
    unsigned short* __restrict__ Xh, unsigned short* __restrict__ Xl,
    float* __restrict__ x2g) {
    int t0 = blockIdx.x * 64;       // 32 tiles
    int sl = blockIdx.y;            // 8 d-slices of 64
    int bn = blockIdx.z;            // 24
    int d0 = sl * 64;
    int tid = threadIdx.x;
    __shared__ float tile[64][65];
#pragma unroll
    for (int i = 0; i < 16; ++i) {
        int idx = tid + 256 * i;
        int dd = idx >> 6, tt = idx & 63;
        tile[dd][tt] = x[((size_t)bn * D_ + d0 + dd) * T_ + t0 + tt];
    }
    __syncthreads();
    int tt = tid >> 2, cp = tid & 3;
    size_t rowbyte = ((size_t)bn * T_ + t0 + tt) * 1024 + (size_t)sl * 128;
    float s2 = 0.f;
#pragma unroll
    for (int cc = 0; cc < 2; ++cc) {
        int c = cp * 2 + cc;
        unsigned int uh[4], ul[4];
#pragma unroll
        for (int q = 0; q < 4; ++q) {
            float v0 = tile[c * 8 + 2*q][tt], v1 = tile[c * 8 + 2*q + 1][tt];
            s2 += v0 * v0 + v1 * v1;
            unsigned short h0 = f2bf(v0), h1 = f2bf(v1);
            float l0 = v0 - bf2f(h0), l1 = v1 - bf2f(h1);
            uh[q] = (unsigned)h0 | ((unsigned)h1 << 16);
            ul[q] = (unsigned)f2bf(l0) | ((unsigned)f2bf(l1) << 16);
        }
        size_t pos = rowbyte + c * 16;
        *(u32x4*)((char*)Xh + pos) = u32x4{uh[0], uh[1], uh[2], uh[3]};
        *(u32x4*)((char*)Xl + pos) = u32x4{ul[0], ul[1], ul[2], ul[3]};
    }
    s2 += __shfl_xor(s2, 1, 64);
    s2 += __shfl_xor(s2, 2, 64);
    if (cp == 0) atomicAdd(&x2g[(size_t)bn * T_ + t0 + tt], s2);
}

// ------------------------------------------------------------- MFMA GEMM
// 256t x 256k tile, 512 thr / 8 waves (2m x 4n), BK=32, dbuf LDS 128KB.
// 2-phase: issue next-step global_load_lds BEFORE the MFMA cluster so the
// end-of-iter __syncthreads (vmcnt0 drain) lands after ~3.7k cyc of MFMA.
__global__ __launch_bounds__(512, 2) void vq_gemm(
    const unsigned short* __restrict__ Xh, const unsigned short* __restrict__ Xl,
    const unsigned short* __restrict__ Eh, const unsigned short* __restrict__ El,
    const float* __restrict__ e2,
    float* __restrict__ pm1, float* __restrict__ pm2, int* __restrict__ pi1) {

    __shared__ char lds[131072];   // 2 bufs x {A_hi,A_lo,B_hi,B_lo} x 16KB
    int tid = threadIdx.x;
    int lane = tid & 63, wid = tid >> 6;
    int bx = blockIdx.x, by = blockIdx.y, bn = blockIdx.z;
    int band = bn % NB_;
    int wm = wid >> 2, wn = wid & 3;
    int rl = lane & 15, cl = lane >> 4;

    // staging: wave pair per matrix; 8 gld16 (8KB) per wave per step
    int smat = wid >> 1;   // 0 Xh, 1 Xl, 2 Eh, 3 El
    const char* srcm = (smat == 0) ? (const char*)Xh : (smat == 1) ? (const char*)Xl
                     : (smat == 2) ? (const char*)Eh : (const char*)El;
    size_t rowbase = (smat < 2) ? ((size_t)bn * T_ + (size_t)bx * 256)
                                : ((size_t)band * K_ + (size_t)by * 256);
    // pre-swizzled global source: chunk c = (l&3) ^ ((l>>3)&3) within 64B
    const char* lane_src = srcm + (rowbase + (wid & 1) * 128 + (lane >> 2)) * 1024
                         + (((lane & 3) ^ ((lane >> 3) & 3)) * 16);
    const int dstoff = (wid >> 1) * 16384 + (wid & 1) * 8192;
    // read-side swizzle (matches writer): 2 lanes/bank = conflict-free
    const int chunkoff = ((cl ^ ((rl >> 1) & 3)) * 16);

    f32x4 acc[8][4];
#pragma unroll
    for (int m = 0; m < 8; ++m)
#pragma unroll
        for (int n = 0; n < 4; ++n) acc[m][n] = f32x4{0.f, 0.f, 0.f, 0.f};

    {   // prologue: stage s=0 into buf0
        char* dp = lds + dstoff;
#pragma unroll
        for (int q = 0; q < 8; ++q) gld16(lane_src + (size_t)q * 16384, dp + q * 1024);
    }
    __syncthreads();

    for (int s = 0; s < 16; ++s) {
        int cur = s & 1;
        if (s < 15) {   // issue next-step staging FIRST (latency hides under MFMA)
            const char* sp = lane_src + (size_t)(s + 1) * 64;
            char* dp = lds + (cur ^ 1) * 65536 + dstoff;
#pragma unroll
            for (int q = 0; q < 8; ++q) gld16(sp + (size_t)q * 16384, dp + q * 1024);
        }
        const char* base = lds + cur * 65536;
        bf16x8 bh[4], bl[4];
#pragma unroll
        for (int n = 0; n < 4; ++n) {
            int boff = (wn * 64 + n * 16 + rl) * 64 + chunkoff;
            bh[n] = *(const bf16x8*)(base + 32768 + boff);
            bl[n] = *(const bf16x8*)(base + 49152 + boff);
        }
#pragma unroll
        for (int m = 0; m < 8; ++m) {
            int aoff = (wm * 128 + m * 16 + rl) * 64 + chunkoff;
            bf16x8 ah = *(const bf16x8*)(base + aoff);
            bf16x8 al = *(const bf16x8*)(base + 16384 + aoff);
#pragma unroll
            for (int n = 0; n < 4; ++n) {
                acc[m][n] = __builtin_amdgcn_mfma_f32_16x16x32_bf16(ah, bh[n], acc[m][n], 0, 0, 0);
                acc[m][n] = __builtin_amdgcn_mfma_f32_16x16x32_bf16(ah, bl[n], acc[m][n], 0, 0, 0);
                acc[m][n] = __builtin_amdgcn_mfma_f32_16x16x32_bf16(al, bh[n], acc[m][n], 0, 0, 0);
            }
        }
        __syncthreads();
    }

    // ---- epilogue: two-min fold (k ascending), butterfly over rl, merge wn
    int kb = by * 256 + wn * 64 + rl;
    float ev[4];
#pragma unroll
    for (int n = 0; n < 4; ++n) ev[n] = e2[band * K_ + kb + n * 16];

    float tm1[32], tm2[32];
    int ti[32];
#pragma unroll
    for (int m = 0; m < 8; ++m)
#pragma unroll
        for (int r = 0; r < 4; ++r) {
            int id = m * 4 + r;
            float a1 = 3.4e38f, a2 = 3.4e38f; int i1 = 0;
#pragma unroll
            for (int n = 0; n < 4; ++n) {
                float v = ev[n] - 2.0f * acc[m][n][r];
                int k = kb + n * 16;
                if (v < a1) { a2 = a1; a1 = v; i1 = k; }
                else if (v < a2) a2 = v;
            }
            tm1[id] = a1; tm2[id] = a2; ti[id] = i1;
        }
#pragma unroll
    for (int id = 0; id < 32; ++id) {
#pragma unroll
        for (int st = 1; st < 16; st <<= 1) {
            float om1 = __shfl_xor(tm1[id], st, 64);
            float om2 = __shfl_xor(tm2[id], st, 64);
            int   oi  = __shfl_xor(ti[id],  st, 64);
            if (om1 < tm1[id] || (om1 == tm1[id] && oi < ti[id])) {
                tm2[id] = fminf(tm1[id], om2); tm1[id] = om1; ti[id] = oi;
            } else {
                tm2[id] = fminf(tm2[id], om1);
            }
        }
    }
    // reuse dead staging LDS for the cross-wn merge
    float* mm1 = (float*)lds;
    float* mm2 = (float*)(lds + 4096);
    int*   mi  = (int*)(lds + 8192);
    if (rl == 0) {
#pragma unroll
        for (int m = 0; m < 8; ++m)
#pragma unroll
            for (int r = 0; r < 4; ++r) {
                int row = wm * 128 + m * 16 + cl * 4 + r;
                mm1[wn * 256 + row] = tm1[m * 4 + r];
                mm2[wn * 256 + row] = tm2[m * 4 + r];
                mi [wn * 256 + row] = ti [m * 4 + r];
            }
    }
    __syncthreads();
    if (tid < 256) {
        float m1 = mm1[tid], m2 = mm2[tid]; int i1 = mi[tid];
#pragma unroll
        for (int j = 1; j < 4; ++j) {
            float b1 = mm1[j * 256 + tid], b2 = mm2[j * 256 + tid];
            int   bi = mi[j * 256 + tid];
            if (b1 < m1 || (b1 == m1 && bi < i1)) { m2 = fminf(m1, b2); m1 = b1; i1 = bi; }
            else m2 = fminf(m2, b1);
        }
        size_t gr = (size_t)bn * T_ + (size_t)bx * 256 + tid;
        pm1[gr * 4 + by] = m1; pm2[gr * 4 + by] = m2; pi1[gr * 4 + by] = i1;
    }
}

// ------------------------------------- gather + refine + loss (no x read)
__global__ __launch_bounds__(256) void gather_kernel(
    const float* __restrict__ x, const float* __restrict__ cb,
    const float* __restrict__ pm1, const float* __restrict__ pm2,
    const int* __restrict__ pi1, const float* __restrict__ x2g,
    float* __restrict__ outq, float* __restrict__ outc,
    float* __restrict__ lossp) {

    int bn = blockIdx.y;
    int n  = bn % NB_;
    int t0 = blockIdx.x * 64;
    int tid = threadIdx.x;
    const float* xb  = x  + (size_t)bn * D_ * T_;
    const float* cbb = cb + (size_t)n * K_ * D_;

    __shared__ int codes_sh[64];
    __shared__ float lrow[64];
    __shared__ int slow_any;
    __shared__ double rv[256];
    __shared__ int    rix[256];
    __shared__ float  qsh[64][65];

    if (tid == 0) slow_any = 0;
    __syncthreads();
    if (tid < 64) {
        size_t gr = (size_t)bn * T_ + t0 + tid;
        float m1 = pm1[gr * 4], m2 = pm2[gr * 4]; int i1 = pi1[gr * 4];
#pragma unroll
        for (int j = 1; j < 4; ++j) {
            float b1 = pm1[gr * 4 + j], b2 = pm2[gr * 4 + j]; int bi = pi1[gr * 4 + j];
            if (b1 < m1) { m2 = fminf(m1, b2); m1 = b1; i1 = bi; }
            else m2 = fminf(m2, b1);
        }
        lrow[tid] = x2g[gr] + m1;   // |x-e|^2 = x2 + (e2 - 2 x.e)
        if (m2 - m1 < MARGIN_) { codes_sh[tid] = -1; slow_any = 1; }
        else codes_sh[tid] = i1;
    }
    __syncthreads();

    if (slow_any) {
        for (int r = 0; r < 64; ++r) {
            if (codes_sh[r] >= 0) continue;   // uniform (shared)
            double best = 1e300; int bi = K_;
            for (int k = tid; k < K_; k += 256) {
                const float* cr = cbb + (size_t)k * D_;
                double ssum = 0.0;
                for (int d = 0; d < D_; ++d) {
                    double diff = (double)xb[(size_t)d * T_ + t0 + r] - (double)cr[d];
                    ssum += diff * diff;
                }
                if (ssum < best) { best = ssum; bi = k; }
            }
            rv[tid] = best; rix[tid] = bi;
            __syncthreads();
            for (int s2 = 128; s2 > 0; s2 >>= 1) {
                if (tid < s2) {
                    if (rv[tid + s2] < rv[tid] ||
                        (rv[tid + s2] == rv[tid] && rix[tid + s2] < rix[tid])) {
                        rv[tid] = rv[tid + s2]; rix[tid] = rix[tid + s2];
                    }
                }
                __syncthreads();
            }
            if (tid == 0) { codes_sh[r] = rix[0]; lrow[r] = (float)rv[0]; }
            __syncthreads();
        }
    }

    if (tid < 64) outc[(size_t)bn * T_ + t0 + tid] = (float)codes_sh[tid];
    __syncthreads();
    if (tid < 64) {
        float ls = lrow[tid];
        for (int off = 32; off > 0; off >>= 1) ls += __shfl_down(ls, off, 64);
        if (tid == 0) atomicAdd(lossp, ls * (1.0f / (float)Q_ELEMS_));
    }

    int lt = tid & 63, l4 = tid >> 6;
    int r4 = tid >> 6, dd0 = tid & 63;
    for (int d0 = 0; d0 < D_; d0 += 64) {
        __syncthreads();
        for (int r = r4; r < 64; r += 4)
            qsh[r][dd0] = cbb[(size_t)codes_sh[r] * D_ + d0 + dd0];
        __syncthreads();
#pragma unroll
        for (int j = 0; j < 16; ++j) {
            int dd = l4 + 4 * j;
            size_t xi = ((size_t)bn * D_ + d0 + dd) * T_ + t0 + lt;
            outq[xi] = qsh[lt][dd];
        }
    }
}

// ---------------------------------------------------------------- launcher
extern "C" void kernel_launch(void* const* d_in, const int* in_sizes, int n_in,
                              void* d_out, int out_size, void* d_ws, size_t ws_size,
                              hipStream_t stream) {
    (void)in_sizes; (void)n_in; (void)out_size; (void)ws_size;
    const float* x  = (const float*)d_in[0];
    const float* cb = (const float*)d_in[1];
    float* out = (float*)d_out;

    float* outq  = out;                       // [B,NB,D,T]
    float* outc  = out + Q_ELEMS_;            // [B,NB,T] as float
    float* lossp = out + Q_ELEMS_ + ROWS_;    // scalar

    // split-bf16 x lives in the (not-yet-written) quantized output region.
    unsigned short* Xh = (unsigned short*)d_out;
    unsigned short* Xl = Xh + Q_ELEMS_;

    char* ws = (char*)d_ws;
    unsigned short* Eh = (unsigned short*)ws;                    // 3 MiB
    unsigned short* El = Eh + (size_t)NB_ * K_ * D_;             // 3 MiB
    float* e2  = (float*)(El + (size_t)NB_ * K_ * D_);           // 12 KiB
    float* x2g = e2 + NB_ * K_;                                  // 192 KiB
    float* pm1 = x2g + ROWS_;                                    // 768 KiB
    float* pm2 = pm1 + (size_t)ROWS_ * 4;                        // 768 KiB
    int*   pi1 = (int*)(pm2 + (size_t)ROWS_ * 4);                // 768 KiB

    zero_ws<<<dim3((ROWS_ + 255) / 256), dim3(256), 0, stream>>>(x2g, lossp);
    convert_e<<<dim3(768), dim3(256), 0, stream>>>(cb, Eh, El, e2);
    convert_x<<<dim3(32, 8, 24), dim3(256), 0, stream>>>(x, Xh, Xl, x2g);
    vq_gemm<<<dim3(8, 4, 24), dim3(512), 0, stream>>>(Xh, Xl, Eh, El, e2, pm1, pm2, pi1);
    gather_kernel<<<dim3(32, 24), dim3(256), 0, stream>>>(
        x, cb, pm1, pm2, pi1, x2g, outq, outc, lossp);
}

// Round 4
// 308.106 us; speedup vs baseline: 4.1182x; 1.4013x over previous
//
#include <hip/hip_runtime.h>

// BandVQ forward: B=8, NB=3, D=512, T=2048, K=1024
// x:        [B, NB, D, T] f32
// codebook: [NB, K, D]    f32
// out: quantized [B,NB,D,T] f32 | codes [B,NB,T] (as float) | commit_loss (1 float)

#define B_ 8
#define NB_ 3
#define D_ 512
#define T_ 2048
#define K_ 1024
#define BN_ (B_*NB_)               // 24
#define ROWS_ (BN_*T_)             // 49152
#define Q_ELEMS_ ((size_t)BN_*D_*T_)  // 25165824
#define MARGIN_ 0.02f
#define FLAGCAP_ 8192
#define RESCAN_BLOCKS_ 128

typedef __attribute__((ext_vector_type(4))) float f32x4;
typedef __attribute__((ext_vector_type(8))) short bf16x8;
typedef __attribute__((ext_vector_type(4))) unsigned int u32x4;

__device__ inline unsigned short f2bf(float f) {
    unsigned u = __builtin_bit_cast(unsigned, f);
    unsigned r = (u + 0x7FFFu + ((u >> 16) & 1u)) >> 16;
    return (unsigned short)r;
}
__device__ inline float bf2f(unsigned short h) {
    unsigned u = ((unsigned)h) << 16;
    return __builtin_bit_cast(float, u);
}
__device__ inline void gld16(const void* g, void* l) {
    __builtin_amdgcn_global_load_lds(
        (const __attribute__((address_space(1))) unsigned int*)g,
        (__attribute__((address_space(3))) unsigned int*)l, 16, 0, 0);
}

// ----------------------------------------------------------- zero ws/loss
__global__ void zero_ws(float* __restrict__ x2g, float* __restrict__ lossp,
                        int* __restrict__ flag_cnt) {
    int i = blockIdx.x * 256 + threadIdx.x;
    if (i < ROWS_) x2g[i] = 0.f;
    if (i == 0) { *lossp = 0.f; *flag_cnt = 0; }
}

// -------------------------------------------------- convert codebook + e2
__global__ __launch_bounds__(256) void convert_e(
    const float* __restrict__ cb,
    unsigned short* __restrict__ Eh, unsigned short* __restrict__ El,
    float* __restrict__ e2) {
    int row = blockIdx.x * 4 + (threadIdx.x >> 6);   // 0..3071 = n*K + k
    int lane = threadIdx.x & 63;
    const float* p = cb + (size_t)row * D_ + lane * 8;
    float v[8];
#pragma unroll
    for (int e = 0; e < 8; ++e) v[e] = p[e];
    double sum = 0.0;
#pragma unroll
    for (int e = 0; e < 8; ++e) sum += (double)v[e] * (double)v[e];
    unsigned int uh[4], ul[4];
#pragma unroll
    for (int q = 0; q < 4; ++q) {
        unsigned short h0 = f2bf(v[2*q]), h1 = f2bf(v[2*q+1]);
        float l0 = v[2*q] - bf2f(h0), l1 = v[2*q+1] - bf2f(h1);
        uh[q] = (unsigned)h0 | ((unsigned)h1 << 16);
        ul[q] = (unsigned)f2bf(l0) | ((unsigned)f2bf(l1) << 16);
    }
    size_t pos = (size_t)row * 1024 + lane * 16;
    *(u32x4*)((char*)Eh + pos) = u32x4{uh[0], uh[1], uh[2], uh[3]};
    *(u32x4*)((char*)El + pos) = u32x4{ul[0], ul[1], ul[2], ul[3]};
    for (int off = 32; off > 0; off >>= 1) sum += __shfl_down(sum, off, 64);
    if (lane == 0) e2[row] = (float)sum;
}

// -------------------------------------------------- convert + transpose x
__global__ __launch_bounds__(256) void convert_x(
    const float* __restrict__ x,
    unsigned short* __restrict__ Xh, unsigned short* __restrict__ Xl,
    float* __restrict__ x2g) {
    int t0 = blockIdx.x * 64;       // 32 tiles
    int sl = blockIdx.y;            // 8 d-slices of 64
    int bn = blockIdx.z;            // 24
    int d0 = sl * 64;
    int tid = threadIdx.x;
    __shared__ float tile[64][65];
#pragma unroll
    for (int i = 0; i < 16; ++i) {
        int idx = tid + 256 * i;
        int dd = idx >> 6, tt = idx & 63;
        tile[dd][tt] = x[((size_t)bn * D_ + d0 + dd) * T_ + t0 + tt];
    }
    __syncthreads();
    int tt = tid >> 2, cp = tid & 3;
    size_t rowbyte = ((size_t)bn * T_ + t0 + tt) * 1024 + (size_t)sl * 128;
    float s2 = 0.f;
#pragma unroll
    for (int cc = 0; cc < 2; ++cc) {
        int c = cp * 2 + cc;
        unsigned int uh[4], ul[4];
#pragma unroll
        for (int q = 0; q < 4; ++q) {
            float v0 = tile[c * 8 + 2*q][tt], v1 = tile[c * 8 + 2*q + 1][tt];
            s2 += v0 * v0 + v1 * v1;
            unsigned short h0 = f2bf(v0), h1 = f2bf(v1);
            float l0 = v0 - bf2f(h0), l1 = v1 - bf2f(h1);
            uh[q] = (unsigned)h0 | ((unsigned)h1 << 16);
            ul[q] = (unsigned)f2bf(l0) | ((unsigned)f2bf(l1) << 16);
        }
        size_t pos = rowbyte + c * 16;
        *(u32x4*)((char*)Xh + pos) = u32x4{uh[0], uh[1], uh[2], uh[3]};
        *(u32x4*)((char*)Xl + pos) = u32x4{ul[0], ul[1], ul[2], ul[3]};
    }
    s2 += __shfl_xor(s2, 1, 64);
    s2 += __shfl_xor(s2, 2, 64);
    if (cp == 0) atomicAdd(&x2g[(size_t)bn * T_ + t0 + tt], s2);
}

// ------------------------------------------------------------- MFMA GEMM
// 256t x 256k tile, 512 thr / 8 waves (2m x 4n), BK=32, dbuf LDS 128KB.
// Counted-vmcnt pipeline: per iter {stage next (8 gld16) -> vmcnt(8) ->
// s_barrier -> ds_read+MFMA -> lgkmcnt(0) -> s_barrier}. Prefetch loads
// never drain to 0 inside the loop (T3/T4-minimum).
__global__ __launch_bounds__(512, 2) void vq_gemm(
    const unsigned short* __restrict__ Xh, const unsigned short* __restrict__ Xl,
    const unsigned short* __restrict__ Eh, const unsigned short* __restrict__ El,
    const float* __restrict__ e2,
    float* __restrict__ pm1, float* __restrict__ pm2, int* __restrict__ pi1) {

    __shared__ char lds[131072];   // 2 bufs x {A_hi,A_lo,B_hi,B_lo} x 16KB
    int tid = threadIdx.x;
    int lane = tid & 63, wid = tid >> 6;
    int bx = blockIdx.x, by = blockIdx.y, bn = blockIdx.z;
    int band = bn % NB_;
    int wm = wid >> 2, wn = wid & 3;
    int rl = lane & 15, cl = lane >> 4;

    int smat = wid >> 1;   // 0 Xh, 1 Xl, 2 Eh, 3 El
    const char* srcm = (smat == 0) ? (const char*)Xh : (smat == 1) ? (const char*)Xl
                     : (smat == 2) ? (const char*)Eh : (const char*)El;
    size_t rowbase = (smat < 2) ? ((size_t)bn * T_ + (size_t)bx * 256)
                                : ((size_t)band * K_ + (size_t)by * 256);
    // pre-swizzled global source: chunk c = (l&3) ^ ((l>>3)&3) within 64B
    const char* lane_src = srcm + (rowbase + (wid & 1) * 128 + (lane >> 2)) * 1024
                         + (((lane & 3) ^ ((lane >> 3) & 3)) * 16);
    const int dstoff = (wid >> 1) * 16384 + (wid & 1) * 8192;
    // read-side swizzle (matches writer): 2 lanes/bank = conflict-free
    const int chunkoff = ((cl ^ ((rl >> 1) & 3)) * 16);

    f32x4 acc[8][4];
#pragma unroll
    for (int m = 0; m < 8; ++m)
#pragma unroll
        for (int n = 0; n < 4; ++n) acc[m][n] = f32x4{0.f, 0.f, 0.f, 0.f};

    {   // prologue: stage s=0 into buf0
        char* dp = lds + dstoff;
#pragma unroll
        for (int q = 0; q < 8; ++q) gld16(lane_src + (size_t)q * 16384, dp + q * 1024);
    }

    for (int s = 0; s < 16; ++s) {
        if (s < 15) {   // issue next-step staging; keep it in flight across MFMA
            const char* sp = lane_src + (size_t)(s + 1) * 64;
            char* dp = lds + ((s + 1) & 1) * 65536 + dstoff;
#pragma unroll
            for (int q = 0; q < 8; ++q) gld16(sp + (size_t)q * 16384, dp + q * 1024);
            __builtin_amdgcn_sched_barrier(0);
            asm volatile("s_waitcnt vmcnt(8)" ::: "memory");   // cur buf done
        } else {
            __builtin_amdgcn_sched_barrier(0);
            asm volatile("s_waitcnt vmcnt(0)" ::: "memory");
        }
        __builtin_amdgcn_sched_barrier(0);
        __builtin_amdgcn_s_barrier();                          // all waves: cur ready

        const char* base = lds + (s & 1) * 65536;
        bf16x8 bh[4], bl[4];
#pragma unroll
        for (int n = 0; n < 4; ++n) {
            int boff = (wn * 64 + n * 16 + rl) * 64 + chunkoff;
            bh[n] = *(const bf16x8*)(base + 32768 + boff);
            bl[n] = *(const bf16x8*)(base + 49152 + boff);
        }
        __builtin_amdgcn_s_setprio(1);
#pragma unroll
        for (int m = 0; m < 8; ++m) {
            int aoff = (wm * 128 + m * 16 + rl) * 64 + chunkoff;
            bf16x8 ah = *(const bf16x8*)(base + aoff);
            bf16x8 al = *(const bf16x8*)(base + 16384 + aoff);
#pragma unroll
            for (int n = 0; n < 4; ++n) {
                acc[m][n] = __builtin_amdgcn_mfma_f32_16x16x32_bf16(ah, bh[n], acc[m][n], 0, 0, 0);
                acc[m][n] = __builtin_amdgcn_mfma_f32_16x16x32_bf16(ah, bl[n], acc[m][n], 0, 0, 0);
                acc[m][n] = __builtin_amdgcn_mfma_f32_16x16x32_bf16(al, bh[n], acc[m][n], 0, 0, 0);
            }
        }
        __builtin_amdgcn_s_setprio(0);
        asm volatile("s_waitcnt lgkmcnt(0)" ::: "memory");     // my reads done
        __builtin_amdgcn_sched_barrier(0);
        __builtin_amdgcn_s_barrier();                          // safe to overwrite
    }

    // ---- epilogue: two-min fold (k ascending), butterfly over rl, merge wn
    int kb = by * 256 + wn * 64 + rl;
    float ev[4];
#pragma unroll
    for (int n = 0; n < 4; ++n) ev[n] = e2[band * K_ + kb + n * 16];

    float tm1[32], tm2[32];
    int ti[32];
#pragma unroll
    for (int m = 0; m < 8; ++m)
#pragma unroll
        for (int r = 0; r < 4; ++r) {
            int id = m * 4 + r;
            float a1 = 3.4e38f, a2 = 3.4e38f; int i1 = 0;
#pragma unroll
            for (int n = 0; n < 4; ++n) {
                float v = ev[n] - 2.0f * acc[m][n][r];
                int k = kb + n * 16;
                if (v < a1) { a2 = a1; a1 = v; i1 = k; }
                else if (v < a2) a2 = v;
            }
            tm1[id] = a1; tm2[id] = a2; ti[id] = i1;
        }
#pragma unroll
    for (int id = 0; id < 32; ++id) {
#pragma unroll
        for (int st = 1; st < 16; st <<= 1) {
            float om1 = __shfl_xor(tm1[id], st, 64);
            float om2 = __shfl_xor(tm2[id], st, 64);
            int   oi  = __shfl_xor(ti[id],  st, 64);
            if (om1 < tm1[id] || (om1 == tm1[id] && oi < ti[id])) {
                tm2[id] = fminf(tm1[id], om2); tm1[id] = om1; ti[id] = oi;
            } else {
                tm2[id] = fminf(tm2[id], om1);
            }
        }
    }
    float* mm1 = (float*)lds;
    float* mm2 = (float*)(lds + 4096);
    int*   mi  = (int*)(lds + 8192);
    __syncthreads();
    if (rl == 0) {
#pragma unroll
        for (int m = 0; m < 8; ++m)
#pragma unroll
            for (int r = 0; r < 4; ++r) {
                int row = wm * 128 + m * 16 + cl * 4 + r;
                mm1[wn * 256 + row] = tm1[m * 4 + r];
                mm2[wn * 256 + row] = tm2[m * 4 + r];
                mi [wn * 256 + row] = ti [m * 4 + r];
            }
    }
    __syncthreads();
    if (tid < 256) {
        float m1 = mm1[tid], m2 = mm2[tid]; int i1 = mi[tid];
#pragma unroll
        for (int j = 1; j < 4; ++j) {
            float b1 = mm1[j * 256 + tid], b2 = mm2[j * 256 + tid];
            int   bi = mi[j * 256 + tid];
            if (b1 < m1 || (b1 == m1 && bi < i1)) { m2 = fminf(m1, b2); m1 = b1; i1 = bi; }
            else m2 = fminf(m2, b1);
        }
        size_t gr = (size_t)bn * T_ + (size_t)bx * 256 + tid;
        pm1[gr * 4 + by] = m1; pm2[gr * 4 + by] = m2; pi1[gr * 4 + by] = i1;
    }
}

// ----------------------------------------- finalize: merge, flag, fast loss
__global__ __launch_bounds__(256) void finalize_kernel(
    const float* __restrict__ pm1, const float* __restrict__ pm2,
    const int* __restrict__ pi1, const float* __restrict__ x2g,
    float* __restrict__ outc, float* __restrict__ lossp,
    int* __restrict__ flag_cnt, int* __restrict__ flag_list) {
    int row = blockIdx.x * 256 + threadIdx.x;   // ROWS_ exact
    size_t r4 = (size_t)row * 4;
    float m1 = pm1[r4], m2 = pm2[r4]; int i1 = pi1[r4];
#pragma unroll
    for (int j = 1; j < 4; ++j) {
        float b1 = pm1[r4 + j], b2 = pm2[r4 + j]; int bi = pi1[r4 + j];
        if (b1 < m1) { m2 = fminf(m1, b2); m1 = b1; i1 = bi; }
        else m2 = fminf(m2, b1);
    }
    float lrow = x2g[row] + m1;   // |x-e|^2 = x2 + (e2 - 2 x.e)
    if (m2 - m1 < MARGIN_) {
        int slot = atomicAdd(flag_cnt, 1);
        if (slot < FLAGCAP_) { flag_list[slot] = row; lrow = 0.f; }
        else outc[row] = (float)i1;   // impossible-overflow fallback
    } else {
        outc[row] = (float)i1;
    }
    for (int off = 32; off > 0; off >>= 1) lrow += __shfl_down(lrow, off, 64);
    __shared__ float ws4[4];
    if ((threadIdx.x & 63) == 0) ws4[threadIdx.x >> 6] = lrow;
    __syncthreads();
    if (threadIdx.x == 0)
        atomicAdd(lossp, (ws4[0] + ws4[1] + ws4[2] + ws4[3]) * (1.0f / (float)Q_ELEMS_));
}

// ------------------------------- rescan flagged rows exactly (fp64), parallel
__global__ __launch_bounds__(256) void rescan_kernel(
    const float* __restrict__ x, const float* __restrict__ cb,
    const int* __restrict__ flag_cnt, const int* __restrict__ flag_list,
    float* __restrict__ outc, float* __restrict__ lossp) {
    int tid = threadIdx.x;
    int cnt = *flag_cnt; if (cnt > FLAGCAP_) cnt = FLAGCAP_;
    __shared__ float xsh[D_];
    __shared__ double rv[256];
    __shared__ int    ri[256];
    for (int i = blockIdx.x; i < cnt; i += RESCAN_BLOCKS_) {
        int row = flag_list[i];
        int bn = row / T_, t = row % T_;
        int band = bn % NB_;
        __syncthreads();
        for (int d = tid; d < D_; d += 256)
            xsh[d] = x[((size_t)bn * D_ + d) * T_ + t];
        __syncthreads();
        double best = 1e300; int bi = K_;
        for (int k = tid; k < K_; k += 256) {   // k ascending per thread
            const float* cr = cb + ((size_t)band * K_ + k) * D_;
            double s = 0.0;
            for (int d = 0; d < D_; d += 4) {
                float4 c4 = *(const float4*)(cr + d);
                double e0 = (double)xsh[d]     - (double)c4.x;
                double e1 = (double)xsh[d + 1] - (double)c4.y;
                double e2v = (double)xsh[d + 2] - (double)c4.z;
                double e3 = (double)xsh[d + 3] - (double)c4.w;
                s += e0 * e0 + e1 * e1 + e2v * e2v + e3 * e3;
            }
            if (s < best) { best = s; bi = k; }
        }
        rv[tid] = best; ri[tid] = bi;
        __syncthreads();
        for (int s2 = 128; s2 > 0; s2 >>= 1) {
            if (tid < s2) {
                if (rv[tid + s2] < rv[tid] ||
                    (rv[tid + s2] == rv[tid] && ri[tid + s2] < ri[tid])) {
                    rv[tid] = rv[tid + s2]; ri[tid] = ri[tid + s2];
                }
            }
            __syncthreads();
        }
        if (tid == 0) {
            outc[row] = (float)ri[0];
            atomicAdd(lossp, (float)(rv[0] * (1.0 / (double)Q_ELEMS_)));
        }
    }
}

// ----------------------------------------------- pure gather + write outq
__global__ __launch_bounds__(256) void gather_out(
    const float* __restrict__ cb, const float* __restrict__ outc,
    float* __restrict__ outq) {
    int t0 = blockIdx.x * 64;    // 32
    int sl = blockIdx.y;         // 8 -> d0
    int bn = blockIdx.z;         // 24
    int d0 = sl * 64;
    int band = bn % NB_;
    int tid = threadIdx.x;
    int wv = tid >> 6, ln = tid & 63;
    __shared__ float qsh[64][65];
    __shared__ int csh[64];
    if (tid < 64) csh[tid] = (int)outc[(size_t)bn * T_ + t0 + tid];
    __syncthreads();
    const float* cbb = cb + (size_t)band * K_ * D_ + d0;
#pragma unroll
    for (int j = 0; j < 16; ++j) {
        int r = wv * 16 + j;
        qsh[r][ln] = cbb[(size_t)csh[r] * D_ + ln];
    }
    __syncthreads();
#pragma unroll
    for (int j = 0; j < 16; ++j) {
        int dd = wv * 16 + j;
        outq[((size_t)bn * D_ + d0 + dd) * T_ + t0 + ln] = qsh[ln][dd];
    }
}

// ---------------------------------------------------------------- launcher
extern "C" void kernel_launch(void* const* d_in, const int* in_sizes, int n_in,
                              void* d_out, int out_size, void* d_ws, size_t ws_size,
                              hipStream_t stream) {
    (void)in_sizes; (void)n_in; (void)out_size; (void)ws_size;
    const float* x  = (const float*)d_in[0];
    const float* cb = (const float*)d_in[1];
    float* out = (float*)d_out;

    float* outq  = out;                       // [B,NB,D,T]
    float* outc  = out + Q_ELEMS_;            // [B,NB,T] as float
    float* lossp = out + Q_ELEMS_ + ROWS_;    // scalar

    // split-bf16 x lives in the (not-yet-written) quantized output region.
    unsigned short* Xh = (unsigned short*)d_out;
    unsigned short* Xl = Xh + Q_ELEMS_;

    char* ws = (char*)d_ws;
    unsigned short* Eh = (unsigned short*)ws;                    // 3 MiB
    unsigned short* El = Eh + (size_t)NB_ * K_ * D_;             // 3 MiB
    float* e2  = (float*)(El + (size_t)NB_ * K_ * D_);           // 12 KiB
    float* x2g = e2 + NB_ * K_;                                  // 192 KiB
    float* pm1 = x2g + ROWS_;                                    // 768 KiB
    float* pm2 = pm1 + (size_t)ROWS_ * 4;                        // 768 KiB
    int*   pi1 = (int*)(pm2 + (size_t)ROWS_ * 4);                // 768 KiB
    int*   flag_cnt  = pi1 + (size_t)ROWS_ * 4;                  // 4 B
    int*   flag_list = flag_cnt + 1;                             // 32 KiB

    zero_ws<<<dim3((ROWS_ + 255) / 256), dim3(256), 0, stream>>>(x2g, lossp, flag_cnt);
    convert_e<<<dim3(768), dim3(256), 0, stream>>>(cb, Eh, El, e2);
    convert_x<<<dim3(32, 8, 24), dim3(256), 0, stream>>>(x, Xh, Xl, x2g);
    vq_gemm<<<dim3(8, 4, 24), dim3(512), 0, stream>>>(Xh, Xl, Eh, El, e2, pm1, pm2, pi1);
    finalize_kernel<<<dim3(ROWS_ / 256), dim3(256), 0, stream>>>(
        pm1, pm2, pi1, x2g, outc, lossp, flag_cnt, flag_list);
    rescan_kernel<<<dim3(RESCAN_BLOCKS_), dim3(256), 0, stream>>>(
        x, cb, flag_cnt, flag_list, outc, lossp);
    gather_out<<<dim3(32, 8, 24), dim3(256), 0, stream>>>(cb, outc, outq);
}